// Round 1
// baseline (739.935 us; speedup 1.0000x reference)
//
#include <hip/hip_runtime.h>
#include <hip/hip_bf16.h>
#include <stdint.h>

// Problem constants: score [2,16,2048,2048] fp32, value [2,16,2048,128] fp32
#define S_DIM 2048
#define D_DIM 128
#define BH_N  32
#define BM    128
#define BK    64
#define ASTR  72   // padded k-stride (bf16 elems) for register-staged LDS tiles

typedef float  f32x4  __attribute__((ext_vector_type(4)));
typedef unsigned int u32x2 __attribute__((ext_vector_type(2)));
typedef unsigned int u32x4 __attribute__((ext_vector_type(4)));
typedef short  bf16x8 __attribute__((ext_vector_type(8)));

// fake_quant one float -> integer-valued bf16 (exact: |q| <= 129 < 256)
__device__ __forceinline__ unsigned short quant1(float v, float inv) {
    float q = rintf(v * inv);              // v_rndne_f32 == jnp.round (RNE)
    q = fminf(fmaxf(q, -129.0f), 127.0f);  // faithful MIN_INT = -129
    // integers |x|<=129 have zero low mantissa bits -> truncation is exact bf16
    return (unsigned short)(__float_as_uint(q) >> 16);
}

// ---------------------------------------------------------------------------
// Kernel 1: quantize value and transpose to vt[bh][d][k] (bf16, k-contiguous)
// Each block: one (bh, 64-wide k-tile), all 128 d.
// ---------------------------------------------------------------------------
__global__ __launch_bounds__(256) void vt_quant_kernel(
        const float* __restrict__ value,
        const float* __restrict__ ks_p,
        unsigned short* __restrict__ vt) {
    __shared__ unsigned short T[D_DIM * ASTR];  // [d][k] padded

    const int bid = blockIdx.x;
    const int bh  = bid >> 5;
    const int k0  = (bid & 31) * BK;
    const float inv = 1.0f / ks_p[0];
    const int tid = threadIdx.x;

    const float* src = value + ((size_t)bh * S_DIM + k0) * D_DIM;

#pragma unroll
    for (int i = 0; i < 8; ++i) {
        int f = tid + 256 * i;          // 0..2047 float4s of the 64x128 tile
        int k  = f >> 5;                // 0..63
        int c4 = (f & 31) * 4;          // d base 0..124
        f32x4 v = *(const f32x4*)(src + (size_t)k * D_DIM + c4);
        T[(c4 + 0) * ASTR + k] = quant1(v.x, inv);
        T[(c4 + 1) * ASTR + k] = quant1(v.y, inv);
        T[(c4 + 2) * ASTR + k] = quant1(v.z, inv);
        T[(c4 + 3) * ASTR + k] = quant1(v.w, inv);
    }
    __syncthreads();

    unsigned short* dst = vt + (size_t)bh * D_DIM * S_DIM + k0;
#pragma unroll
    for (int i = 0; i < 2; ++i) {
        int c = tid + 256 * i;          // 512 16B-chunks (128 d x 4 chunks... 8/row)
        int n = c >> 3;                 // d row 0..127... wait 512/8 = 64? no:
        // 128 rows x 64 k = 8192 ushort = 512 chunks of 8 ushorts -> n = c>>2?
        // careful: 64 k = 8 ushort-chunks of 8 -> chunks per row = 8, rows = 64?
        // rows = 128 -> total chunks = 128*8 = 1024. Use 4 iterations instead.
        (void)n;
    }
    // redo write-out correctly: 1024 chunks of 16B, 4 per thread
#pragma unroll
    for (int i = 0; i < 4; ++i) {
        int c = tid + 256 * i;          // 0..1023
        int n = c >> 3;                 // d row 0..127
        int q = (c & 7) * 8;            // k offset within tile
        u32x4 x = *(const u32x4*)(&T[n * ASTR + q]);
        *(u32x4*)(dst + (size_t)n * S_DIM + q) = x;
    }
}

// ---------------------------------------------------------------------------
// Kernel 2: fused quantize(score) + bf16 MFMA GEMM.
// Block = 256 thr (4 waves). Tile: 128(M) x 128(N=D) x K=2048, BK=64.
// Wave w: 64x64 quadrant, 4x4 grid of 16x16x32 MFMAs.
// A: register-staged (fp32->quant->bf16->LDS, stride 72).
// B: global_load_lds dwordx4 from pre-quantized vt, chunk-XOR swizzle.
// ---------------------------------------------------------------------------
__global__ __launch_bounds__(256, 2) void bmm_kernel(
        const float* __restrict__ score,
        const unsigned short* __restrict__ vt,
        const float* __restrict__ qs_p,
        const float* __restrict__ ks_p,
        float* __restrict__ out) {
    __shared__ unsigned short As[BM * ASTR];   // [m][k] padded, 18432 B
    __shared__ unsigned short Bs[D_DIM * BK];  // [n][k] chunk-swizzled, 16384 B

    const int bid = blockIdx.x;
    const int bh  = bid >> 4;
    const int m0  = (bid & 15) * BM;

    const float qs  = qs_p[0];
    const float inv_qs = 1.0f / qs;
    const float fin = qs * ks_p[0];

    const int tid  = threadIdx.x;
    const int lane = tid & 63;
    const int wave = tid >> 6;
    const int wm   = (wave >> 1) * 64;
    const int wn   = (wave & 1) * 64;
    const int m16  = lane & 15;
    const int quad = lane >> 4;

    const float* A = score + (size_t)bh * S_DIM * S_DIM + (size_t)m0 * S_DIM;
    const unsigned short* Bt = vt + (size_t)bh * D_DIM * S_DIM;

    f32x4 acc[4][4] = {};

    for (int kb = 0; kb < S_DIM; kb += BK) {
        // ---- B tile: async global->LDS, 16 KB, 4 chunk-instructions/thread
#pragma unroll
        for (int i = 0; i < 4; ++i) {
            int p  = i * 256 + tid;          // physical 16B chunk 0..1023
            int n  = p >> 3;                 // d row
            int ql = (p & 7) ^ (n & 7);      // XOR swizzle on k-chunk
            const unsigned short* g = Bt + (size_t)n * S_DIM + kb + ql * 8;
            __builtin_amdgcn_global_load_lds(
                (const __attribute__((address_space(1))) void*)g,
                (__attribute__((address_space(3))) void*)(Bs + p * 8),
                16, 0, 0);
        }
        // ---- A tile: 128x64 fp32 -> quantized bf16 in LDS
#pragma unroll
        for (int i = 0; i < 8; ++i) {
            int f = tid + 256 * i;           // 0..2047 float4s
            int r = f >> 4;                  // m row 0..127
            int c = (f & 15) * 4;            // k col 0..60
            f32x4 v = *(const f32x4*)(A + (size_t)r * S_DIM + kb + c);
            unsigned int w0 = (unsigned int)quant1(v.x, inv_qs) |
                              ((unsigned int)quant1(v.y, inv_qs) << 16);
            unsigned int w1 = (unsigned int)quant1(v.z, inv_qs) |
                              ((unsigned int)quant1(v.w, inv_qs) << 16);
            u32x2 wv; wv.x = w0; wv.y = w1;
            *(u32x2*)(&As[r * ASTR + c]) = wv;
        }
        __syncthreads();

        // ---- MFMA: 2 k-substeps of 32
#pragma unroll
        for (int kk = 0; kk < BK; kk += 32) {
            bf16x8 af[4], bf[4];
#pragma unroll
            for (int i = 0; i < 4; ++i)
                af[i] = *(const bf16x8*)(&As[(wm + i * 16 + m16) * ASTR + kk + quad * 8]);
#pragma unroll
            for (int j = 0; j < 4; ++j) {
                int n  = wn + j * 16 + m16;
                int ch = ((kk >> 3) + quad) ^ (n & 7);
                bf[j] = *(const bf16x8*)(&Bs[(n * 8 + ch) * 8]);
            }
#pragma unroll
            for (int i = 0; i < 4; ++i)
#pragma unroll
                for (int j = 0; j < 4; ++j)
                    acc[i][j] = __builtin_amdgcn_mfma_f32_16x16x32_bf16(
                        af[i], bf[j], acc[i][j], 0, 0, 0);
        }
        __syncthreads();
    }

    // ---- epilogue: C/D layout col=lane&15, row=quad*4+reg
    float* O = out + (size_t)bh * S_DIM * D_DIM
                   + (size_t)(m0 + wm + quad * 4) * D_DIM + wn + m16;
#pragma unroll
    for (int i = 0; i < 4; ++i)
#pragma unroll
        for (int r = 0; r < 4; ++r)
#pragma unroll
            for (int j = 0; j < 4; ++j)
                O[(size_t)(i * 16 + r) * D_DIM + j * 16] = acc[i][j][r] * fin;
}

extern "C" void kernel_launch(void* const* d_in, const int* in_sizes, int n_in,
                              void* d_out, int out_size, void* d_ws, size_t ws_size,
                              hipStream_t stream) {
    const float* score = (const float*)d_in[0];
    const float* value = (const float*)d_in[1];
    const float* qs    = (const float*)d_in[2];
    const float* ks    = (const float*)d_in[3];
    float* out = (float*)d_out;
    unsigned short* vt = (unsigned short*)d_ws;  // needs 32*128*2048*2 = 16 MiB

    // 1) quantize+transpose value -> vt[bh][d][k]
    vt_quant_kernel<<<BH_N * (S_DIM / BK), 256, 0, stream>>>(value, ks, vt);
    // 2) fused quantize(score) + GEMM
    bmm_kernel<<<BH_N * (S_DIM / BM), 256, 0, stream>>>(score, vt, qs, ks, out);
}

// Round 2
// 718.874 us; speedup vs baseline: 1.0293x; 1.0293x over previous
//
#include <hip/hip_runtime.h>
#include <hip/hip_bf16.h>
#include <stdint.h>

// Problem: score [2,16,2048,2048] fp32, value [2,16,2048,128] fp32
// out[bh] = (fq(score) . fq(value)) * qs*ks  -- integer-valued matmul, exact in bf16 MFMA
#define S_DIM 2048
#define D_DIM 128
#define BH_N  32
#define BM    64    // 1024 blocks -> 4 blocks/CU (was 128 -> only 2/CU)
#define BK    64
#define ASTR  72    // padded k-stride (bf16) for A tile; rows 16B-aligned

typedef float  f32x4  __attribute__((ext_vector_type(4)));
typedef unsigned int u32x2 __attribute__((ext_vector_type(2)));
typedef unsigned int u32x4 __attribute__((ext_vector_type(4)));
typedef short  bf16x8 __attribute__((ext_vector_type(8)));

// fake_quant one float -> integer-valued bf16 (exact: |q| <= 129 < 256)
__device__ __forceinline__ unsigned short quant1(float v, float inv) {
    float q = rintf(v * inv);              // v_rndne_f32 == jnp.round (RNE)
    q = fminf(fmaxf(q, -129.0f), 127.0f);  // faithful MIN_INT = -129
    return (unsigned short)(__float_as_uint(q) >> 16);  // exact bf16 truncation
}

// ---------------------------------------------------------------------------
// Kernel 1: quantize value and transpose to vt[bh][d][k] (bf16, k-contiguous)
// ---------------------------------------------------------------------------
__global__ __launch_bounds__(256) void vt_quant_kernel(
        const float* __restrict__ value,
        const float* __restrict__ ks_p,
        unsigned short* __restrict__ vt) {
    __shared__ unsigned short T[D_DIM * ASTR];  // [d][k] padded

    const int bid = blockIdx.x;
    const int bh  = bid >> 5;
    const int k0  = (bid & 31) * BK;
    const float inv = 1.0f / ks_p[0];
    const int tid = threadIdx.x;

    const float* src = value + ((size_t)bh * S_DIM + k0) * D_DIM;

#pragma unroll
    for (int i = 0; i < 8; ++i) {
        int f  = tid + 256 * i;         // 0..2047 float4s of the 64x128 tile
        int k  = f >> 5;                // 0..63
        int c4 = (f & 31) * 4;          // d base 0..124
        f32x4 v = *(const f32x4*)(src + (size_t)k * D_DIM + c4);
        T[(c4 + 0) * ASTR + k] = quant1(v.x, inv);
        T[(c4 + 1) * ASTR + k] = quant1(v.y, inv);
        T[(c4 + 2) * ASTR + k] = quant1(v.z, inv);
        T[(c4 + 3) * ASTR + k] = quant1(v.w, inv);
    }
    __syncthreads();

    unsigned short* dst = vt + (size_t)bh * D_DIM * S_DIM + k0;
#pragma unroll
    for (int i = 0; i < 4; ++i) {
        int c = tid + 256 * i;          // 0..1023 16B-chunks (128 d x 8 chunks)
        int n = c >> 3;                 // d row 0..127
        int q = (c & 7) * 8;            // k offset within tile
        u32x4 x = *(const u32x4*)(&T[n * ASTR + q]);
        *(u32x4*)(dst + (size_t)n * S_DIM + q) = x;
    }
}

// ---------------------------------------------------------------------------
// Kernel 2: fused quantize(score) + bf16 MFMA GEMM.
// 1024 blocks (bh x 32 m-tiles), 256 thr (4 waves, 2x2 grid of 32x64).
// Tile: 64(M) x 128(N=D) x BK=64.
// A: register-staged fp32 -> quant -> bf16 LDS (stride 72).
// B: global_load_lds dwordx4 from pre-quantized vt, chunk-XOR swizzle.
// ---------------------------------------------------------------------------
__global__ __launch_bounds__(256, 4) void bmm_kernel(
        const float* __restrict__ score,
        const unsigned short* __restrict__ vt,
        const float* __restrict__ qs_p,
        const float* __restrict__ ks_p,
        float* __restrict__ out) {
    __shared__ unsigned short As[BM * ASTR];   // 9216 B
    __shared__ unsigned short Bs[D_DIM * BK];  // 16384 B

    const int bid = blockIdx.x;
    const int bh  = bid >> 5;                  // 32 m-tiles per bh
    const int m0  = (bid & 31) * BM;

    const float qs  = qs_p[0];
    const float inv_qs = 1.0f / qs;
    const float fin = qs * ks_p[0];

    const int tid  = threadIdx.x;
    const int lane = tid & 63;
    const int wave = tid >> 6;
    const int wm   = (wave >> 1) * 32;
    const int wn   = (wave & 1) * 64;
    const int m16  = lane & 15;
    const int quad = lane >> 4;

    const float* A = score + (size_t)bh * S_DIM * S_DIM + (size_t)m0 * S_DIM;
    const unsigned short* Bt = vt + (size_t)bh * D_DIM * S_DIM;

    f32x4 acc[2][4] = {};

    for (int kb = 0; kb < S_DIM; kb += BK) {
        // ---- B tile: async global->LDS, 16 KB, 4 chunk-instructions/thread
#pragma unroll
        for (int i = 0; i < 4; ++i) {
            int p  = i * 256 + tid;          // physical 16B chunk 0..1023
            int n  = p >> 3;                 // d row
            int ql = (p & 7) ^ (n & 7);      // XOR swizzle on k-chunk
            const unsigned short* g = Bt + (size_t)n * S_DIM + kb + ql * 8;
            __builtin_amdgcn_global_load_lds(
                (const __attribute__((address_space(1))) void*)g,
                (__attribute__((address_space(3))) void*)(Bs + p * 8),
                16, 0, 0);
        }
        // ---- A tile: 64x64 fp32 -> quantized bf16 in LDS (1024 float4s)
#pragma unroll
        for (int i = 0; i < 4; ++i) {
            int f = tid + 256 * i;
            int r = f >> 4;                  // m row 0..63
            int c = (f & 15) * 4;            // k col 0..60
            f32x4 v = __builtin_nontemporal_load(
                (const f32x4*)(A + (size_t)r * S_DIM + kb + c));
            unsigned int w0 = (unsigned int)quant1(v.x, inv_qs) |
                              ((unsigned int)quant1(v.y, inv_qs) << 16);
            unsigned int w1 = (unsigned int)quant1(v.z, inv_qs) |
                              ((unsigned int)quant1(v.w, inv_qs) << 16);
            u32x2 wv; wv.x = w0; wv.y = w1;
            *(u32x2*)(&As[r * ASTR + c]) = wv;
        }
        __syncthreads();

        // ---- MFMA: 2 k-substeps of 32
#pragma unroll
        for (int kk = 0; kk < BK; kk += 32) {
            bf16x8 af[2], bf[4];
#pragma unroll
            for (int i = 0; i < 2; ++i)
                af[i] = *(const bf16x8*)(&As[(wm + i * 16 + m16) * ASTR + kk + quad * 8]);
#pragma unroll
            for (int j = 0; j < 4; ++j) {
                int n  = wn + j * 16 + m16;
                int ch = ((kk >> 3) + quad) ^ (n & 7);
                bf[j] = *(const bf16x8*)(&Bs[(n * 8 + ch) * 8]);
            }
#pragma unroll
            for (int i = 0; i < 2; ++i)
#pragma unroll
                for (int j = 0; j < 4; ++j)
                    acc[i][j] = __builtin_amdgcn_mfma_f32_16x16x32_bf16(
                        af[i], bf[j], acc[i][j], 0, 0, 0);
        }
        __syncthreads();
    }

    // ---- epilogue: C/D layout col=lane&15, row=quad*4+reg
    float* O = out + (size_t)bh * S_DIM * D_DIM
                   + (size_t)(m0 + wm + quad * 4) * D_DIM + wn + m16;
#pragma unroll
    for (int i = 0; i < 2; ++i)
#pragma unroll
        for (int r = 0; r < 4; ++r)
#pragma unroll
            for (int j = 0; j < 4; ++j)
                O[(size_t)(i * 16 + r) * D_DIM + j * 16] = acc[i][j][r] * fin;
}

extern "C" void kernel_launch(void* const* d_in, const int* in_sizes, int n_in,
                              void* d_out, int out_size, void* d_ws, size_t ws_size,
                              hipStream_t stream) {
    const float* score = (const float*)d_in[0];
    const float* value = (const float*)d_in[1];
    const float* qs    = (const float*)d_in[2];
    const float* ks    = (const float*)d_in[3];
    float* out = (float*)d_out;
    unsigned short* vt = (unsigned short*)d_ws;  // 32*128*2048*2 = 16 MiB

    vt_quant_kernel<<<BH_N * (S_DIM / BK), 256, 0, stream>>>(value, ks, vt);
    bmm_kernel<<<BH_N * (S_DIM / BM), 256, 0, stream>>>(score, vt, qs, ks, out);
}